// Round 3
// baseline (228.175 us; speedup 1.0000x reference)
//
#include <hip/hip_runtime.h>

// GraphProjection: out[N,963] = concat(verts[N,3], proj(f0)[N,64], proj(f1)[N,128],
//                                      proj(f2)[N,256], proj(f3)[N,512])
// Degenerate "bilinear": weights collapse to w11 = (x2-x1)*(y2-y1) in {0,1};
// every feature element is a masked gather of feat[c, floor(x), floor(y)].
//
// V4: wave-per-vertex row copy with
//  - params computed inline per wave (wave-uniform, readfirstlane -> SGPR);
//    prep_params dispatch eliminated on the fast path
//  - NONTEMPORAL stores for out: 192.6 MB write stream no longer thrashes L2,
//    keeping the 1.5 MB transposed feature tables L2-resident for the reads
//  - 963-dword row copied in 15 unrolled lane-dense iterations + 3-lane tail;
//    offsets < 0 redirect to a zero block (no per-element select)

static constexpr int NV      = 50000;
static constexpr int TOTAL   = 963 * NV;          // 48,150,000

// transposed feature sizes (floats): [S*S, C]
static constexpr int T0 = 56 * 56 * 64;   // 200,704
static constexpr int T1 = 28 * 28 * 128;  // 100,352
static constexpr int T2 = 14 * 14 * 256;  // 50,176
static constexpr int T3 = 7 * 7 * 512;    // 25,088
static constexpr int TSUM = T0 + T1 + T2 + T3; // 376,320
static constexpr int ZN   = 516;          // zero block (covers col-448 up to 514)

__device__ __forceinline__ void proj_hw(const float* __restrict__ verts, int n,
                                        float& h, float& w) {
  float v0 = verts[3 * n + 0];
  float v1 = verts[3 * n + 1];
  float v2 = verts[3 * n + 2];
  // match numpy fp32 exactly: no FMA contraction, IEEE rn division
  h = __fadd_rn(__fmul_rn(248.0f, __fdiv_rn(v1, v2)), 111.5f);
  w = __fadd_rn(__fmul_rn(248.0f, __fdiv_rn(v0, -v2)), 111.5f);
  h = fminf(fmaxf(h, 0.0f), 223.0f);
  w = fminf(fmaxf(w, 0.0f), 223.0f);
}

__device__ __forceinline__ int level_off(float h, float w, float scale, int S) {
  float x = h * scale;  // scale = S/224 is an exact power of two
  float y = w * scale;
  int x1 = (int)floorf(x);
  int x2 = min((int)ceilf(x), S - 1);
  int y1 = (int)floorf(y);
  int y2 = min((int)ceilf(y), S - 1);
  return (x2 > x1 && y2 > y1) ? (x1 * S + y1) : -1;
}

// [C,S,S] -> [S*S, C] so per-wave channel reads are contiguous; also zero-fills
// the ZN-float zero block used for out-of-image vertices.
__global__ __launch_bounds__(256) void transpose_k(
    const float* __restrict__ f0, const float* __restrict__ f1,
    const float* __restrict__ f2, const float* __restrict__ f3,
    float* __restrict__ t0, float* __restrict__ t1,
    float* __restrict__ t2, float* __restrict__ t3,
    float* __restrict__ zeros) {
  int i = blockIdx.x * 256 + threadIdx.x;
  if (i < T0) { int off = i >> 6, c = i & 63;  t0[i] = f0[c * 3136 + off]; return; }
  i -= T0;
  if (i < T1) { int off = i >> 7, c = i & 127; t1[i] = f1[c * 784 + off];  return; }
  i -= T1;
  if (i < T2) { int off = i >> 8, c = i & 255; t2[i] = f2[c * 196 + off];  return; }
  i -= T2;
  if (i < T3) { int off = i >> 9, c = i & 511; t3[i] = f3[c * 49 + off];   return; }
  i -= T3;
  if (i < ZN) zeros[i] = 0.0f;
}

// Wave-per-vertex: 64 lanes copy one 963-dword output row.
// Region bases are wave-uniform (SGPR); cols [0,3)=verts, [3,67)=t0,
// [67,195)=t1, [195,451)=t2, [451,963)=t3.
__global__ __launch_bounds__(256) void gp_row_k(
    const float* __restrict__ verts,
    const float* __restrict__ t0, const float* __restrict__ t1,
    const float* __restrict__ t2, const float* __restrict__ t3,
    const float* __restrict__ zeros,
    float* __restrict__ out) {
  int wid  = (blockIdx.x * 256 + threadIdx.x) >> 6;
  int lane = threadIdx.x & 63;
  if (wid >= NV) return;
  const int n = wid;

  // wave-uniform projection: every lane computes identical values (broadcast
  // loads + uniform arithmetic); force into SGPRs for saddr-form addressing
  float h, w;
  proj_hw(verts, n, h, w);
  int p0 = __builtin_amdgcn_readfirstlane(level_off(h, w, 0.25f,    56));
  int p1 = __builtin_amdgcn_readfirstlane(level_off(h, w, 0.125f,   28));
  int p2 = __builtin_amdgcn_readfirstlane(level_off(h, w, 0.0625f,  14));
  int p3 = __builtin_amdgcn_readfirstlane(level_off(h, w, 0.03125f, 7));

  // s_r[col] is valid for col in region r; p<0 redirects into the zero block
  const float* vb = verts + 3 * n;                                  // col in [0,3)
  const float* s0 = ((p0 >= 0) ? t0 + (p0 << 6) : zeros + 3) - 3;   // [3,67)
  const float* s1 = ((p1 >= 0) ? t1 + (p1 << 7) : zeros + 3) - 67;  // [67,195)
  const float* s2 = ((p2 >= 0) ? t2 + (p2 << 8) : zeros + 3) - 195; // [195,451)
  const float* s3 = ((p3 >= 0) ? t3 + (p3 << 9) : zeros + 3) - 451; // [451,963)

  float* o = out + 963 * n;

#pragma unroll
  for (int k = 0; k < 15; ++k) {
    int col = (k << 6) + lane;
    // with k unrolled, 11/15 iterations fold to a single region at compile time
    const float* b = (col < 3)   ? vb
                   : (col < 67)  ? s0
                   : (col < 195) ? s1
                   : (col < 451) ? s2
                   :               s3;
    __builtin_nontemporal_store(b[col], o + col);
  }
  if (lane < 3) {
    int col = 960 + lane;
    __builtin_nontemporal_store(s3[col], o + col);
  }
}

// ---------- fallback paths (small workspace) ----------
template <int MODE>
__device__ __forceinline__ int get_off(const int* __restrict__ params,
                                       const float* __restrict__ verts,
                                       int n, int k, float scale, int S) {
  if (MODE < 2) return params[4 * n + k];
  float h, w;
  proj_hw(verts, n, h, w);
  return level_off(h, w, scale, S);
}

__global__ __launch_bounds__(256) void prep_params_k(const float* __restrict__ verts,
                                                     int* __restrict__ params) {
  int n = blockIdx.x * 256 + threadIdx.x;
  if (n >= NV) return;
  float h, w;
  proj_hw(verts, n, h, w);
  params[4 * n + 0] = level_off(h, w, 0.25f,    56);
  params[4 * n + 1] = level_off(h, w, 0.125f,   28);
  params[4 * n + 2] = level_off(h, w, 0.0625f,  14);
  params[4 * n + 3] = level_off(h, w, 0.03125f, 7);
}

static constexpr int B_VERTS = 3 * NV;            // 150,000
static constexpr int B_F0    = B_VERTS + 64 * NV; // 3,350,000
static constexpr int B_F1    = B_F0 + 128 * NV;   // 9,750,000
static constexpr int B_F2    = B_F1 + 256 * NV;   // 22,550,000

template <int MODE>
__global__ __launch_bounds__(256) void gp_main_k(
    const float* __restrict__ verts,
    const float* __restrict__ f0, const float* __restrict__ f1,
    const float* __restrict__ f2, const float* __restrict__ f3,
    const int* __restrict__ params, float* __restrict__ out) {
  int j = blockIdx.x * 256 + threadIdx.x;
  if (j >= TOTAL) return;

  if (j < B_VERTS) {
    int n = j / 3;
    int col = j - 3 * n;
    out[n * 963 + col] = verts[j];
    return;
  }

  int n, outcol;
  float val = 0.0f;
  if (j < B_F0) {
    int t = j - B_VERTS; n = t >> 6; int c = t & 63;
    int off = get_off<MODE>(params, verts, n, 0, 0.25f, 56);
    if (off >= 0) val = f0[c * 3136 + off];
    outcol = 3 + c;
  } else if (j < B_F1) {
    int t = j - B_F0; n = t >> 7; int c = t & 127;
    int off = get_off<MODE>(params, verts, n, 1, 0.125f, 28);
    if (off >= 0) val = f1[c * 784 + off];
    outcol = 67 + c;
  } else if (j < B_F2) {
    int t = j - B_F1; n = t >> 8; int c = t & 255;
    int off = get_off<MODE>(params, verts, n, 2, 0.0625f, 14);
    if (off >= 0) val = f2[c * 196 + off];
    outcol = 195 + c;
  } else {
    int t = j - B_F2; n = t >> 9; int c = t & 511;
    int off = get_off<MODE>(params, verts, n, 3, 0.03125f, 7);
    if (off >= 0) val = f3[c * 49 + off];
    outcol = 451 + c;
  }
  out[n * 963 + outcol] = val;
}

extern "C" void kernel_launch(void* const* d_in, const int* in_sizes, int n_in,
                              void* d_out, int out_size, void* d_ws, size_t ws_size,
                              hipStream_t stream) {
  const float* f0    = (const float*)d_in[0];
  const float* f1    = (const float*)d_in[1];
  const float* f2    = (const float*)d_in[2];
  const float* f3    = (const float*)d_in[3];
  const float* verts = (const float*)d_in[4];
  float* out = (float*)d_out;

  const size_t PARAM_BYTES = (size_t)NV * 4 * sizeof(int);       // 800,000
  const size_t FAST_BYTES  = (size_t)(TSUM + ZN) * sizeof(float); // 1,507,344

  if (ws_size >= FAST_BYTES) {
    float* t0 = (float*)d_ws;
    float* t1 = t0 + T0;
    float* t2 = t1 + T1;
    float* t3 = t2 + T2;
    float* zeros = t3 + T3;
    transpose_k<<<(TSUM + ZN + 255) / 256, 256, 0, stream>>>(f0, f1, f2, f3,
                                                             t0, t1, t2, t3, zeros);
    const int rowBlocks = (NV * 64 + 255) / 256;  // 12,500 (one wave per vertex)
    gp_row_k<<<rowBlocks, 256, 0, stream>>>(verts, t0, t1, t2, t3, zeros, out);
  } else if (ws_size >= PARAM_BYTES) {
    int* params = (int*)d_ws;
    prep_params_k<<<(NV + 255) / 256, 256, 0, stream>>>(verts, params);
    gp_main_k<1><<<(TOTAL + 255) / 256, 256, 0, stream>>>(verts, f0, f1, f2, f3, params, out);
  } else {
    gp_main_k<2><<<(TOTAL + 255) / 256, 256, 0, stream>>>(verts, f0, f1, f2, f3, nullptr, out);
  }
}

// Round 4
// 200.656 us; speedup vs baseline: 1.1371x; 1.1371x over previous
//
#include <hip/hip_runtime.h>

// GraphProjection: out[N,963] = concat(verts[N,3], proj(f0)[N,64], proj(f1)[N,128],
//                                      proj(f2)[N,256], proj(f3)[N,512])
// Degenerate "bilinear": weights collapse to w11 = (x2-x1)*(y2-y1) in {0,1};
// every feature element is a masked gather of feat[c, floor(x), floor(y)].
//
// V5: wave-per-vertex row copy, float4 both sides.
//  - region boundaries {3,67,195,451} are all ==3 (mod 4): a x4 grid anchored
//    at col 3 never crosses a region inside a group; slice bases are >=256B
//    aligned so ALL loads are aligned global_load_dwordx4.
//  - stores are dwordx4 at 4B alignment via memcpy (legal+fast on gfx950).
//  - plain stores (NT stores measured -20us in V4: write stream wants L2).
//  - params computed inline per wave (wave-uniform, readfirstlane -> SGPR).
//  - cols 0..2 stored from the vert registers already loaded for projection.

static constexpr int NV      = 50000;
static constexpr int TOTAL   = 963 * NV;          // 48,150,000

// transposed feature sizes (floats): [S*S, C]
static constexpr int T0 = 56 * 56 * 64;   // 200,704
static constexpr int T1 = 28 * 28 * 128;  // 100,352
static constexpr int T2 = 14 * 14 * 256;  // 50,176
static constexpr int T3 = 7 * 7 * 512;    // 25,088
static constexpr int TSUM = T0 + T1 + T2 + T3; // 376,320
static constexpr int ZN   = 516;          // zero block (>=512 needed)

typedef float f32x4 __attribute__((ext_vector_type(4)));

__device__ __forceinline__ void store4_u(float* p, f32x4 v) {
  __builtin_memcpy(p, &v, 16);  // 4B-aligned dwordx4 store
}

__device__ __forceinline__ int level_off(float h, float w, float scale, int S) {
  float x = h * scale;  // scale = S/224 is an exact power of two
  float y = w * scale;
  int x1 = (int)floorf(x);
  int x2 = min((int)ceilf(x), S - 1);
  int y1 = (int)floorf(y);
  int y2 = min((int)ceilf(y), S - 1);
  return (x2 > x1 && y2 > y1) ? (x1 * S + y1) : -1;
}

// [C,S,S] -> [S*S, C] so per-wave channel reads are contiguous; also zero-fills
// the ZN-float zero block used for out-of-image vertices.
__global__ __launch_bounds__(256) void transpose_k(
    const float* __restrict__ f0, const float* __restrict__ f1,
    const float* __restrict__ f2, const float* __restrict__ f3,
    float* __restrict__ t0, float* __restrict__ t1,
    float* __restrict__ t2, float* __restrict__ t3,
    float* __restrict__ zeros) {
  int i = blockIdx.x * 256 + threadIdx.x;
  if (i < T0) { int off = i >> 6, c = i & 63;  t0[i] = f0[c * 3136 + off]; return; }
  i -= T0;
  if (i < T1) { int off = i >> 7, c = i & 127; t1[i] = f1[c * 784 + off];  return; }
  i -= T1;
  if (i < T2) { int off = i >> 8, c = i & 255; t2[i] = f2[c * 196 + off];  return; }
  i -= T2;
  if (i < T3) { int off = i >> 9, c = i & 511; t3[i] = f3[c * 49 + off];   return; }
  i -= T3;
  if (i < ZN) zeros[i] = 0.0f;
}

// Wave-per-vertex: 64 lanes copy one 963-dword output row with x4 accesses.
// Cols [0,3)=verts, [3,67)=t0, [67,195)=t1, [195,451)=t2, [451,963)=t3.
// s_r is positioned so s_r[col] is the right element for col in region r;
// s_r + col is 16B-aligned for col on the x4 grid (col == 3 mod 4).
__global__ __launch_bounds__(256) void gp_row_k(
    const float* __restrict__ verts,
    const float* __restrict__ t0, const float* __restrict__ t1,
    const float* __restrict__ t2, const float* __restrict__ t3,
    const float* __restrict__ zeros,
    float* __restrict__ out) {
  int wid  = (blockIdx.x * 256 + threadIdx.x) >> 6;
  int lane = threadIdx.x & 63;
  if (wid >= NV) return;
  const int n = wid;

  // wave-uniform projection (broadcast loads, identical lanes)
  float v0 = verts[3 * n + 0];
  float v1 = verts[3 * n + 1];
  float v2 = verts[3 * n + 2];
  // match numpy fp32 exactly: no FMA contraction, IEEE rn division
  float h = __fadd_rn(__fmul_rn(248.0f, __fdiv_rn(v1, v2)), 111.5f);
  float w = __fadd_rn(__fmul_rn(248.0f, __fdiv_rn(v0, -v2)), 111.5f);
  h = fminf(fmaxf(h, 0.0f), 223.0f);
  w = fminf(fmaxf(w, 0.0f), 223.0f);

  int p0 = __builtin_amdgcn_readfirstlane(level_off(h, w, 0.25f,    56));
  int p1 = __builtin_amdgcn_readfirstlane(level_off(h, w, 0.125f,   28));
  int p2 = __builtin_amdgcn_readfirstlane(level_off(h, w, 0.0625f,  14));
  int p3 = __builtin_amdgcn_readfirstlane(level_off(h, w, 0.03125f, 7));

  // p<0 redirects into the zero block; zeros - start_r keeps 16B alignment
  // since (col - start_r) == 0 (mod 4) on the x4 grid.
  const float* s0 = ((p0 >= 0) ? t0 + (p0 << 6) : zeros) - 3;
  const float* s1 = ((p1 >= 0) ? t1 + (p1 << 7) : zeros) - 67;
  const float* s2 = ((p2 >= 0) ? t2 + (p2 << 8) : zeros) - 195;
  const float* s3 = ((p3 >= 0) ? t3 + (p3 << 9) : zeros) - 451;

  float* o = out + 963 * n;

  // head: cols 0..2 from the vert registers (3 lanes)
  if (lane < 3) o[lane] = (lane == 0) ? v0 : (lane == 1) ? v1 : v2;

  // k=0: cols 3+4*lane in [3,259): t0 (lane<16), t1 (lane<48), t2 (else)
  {
    int col = 3 + 4 * lane;
    const float* b = (lane < 16) ? s0 : (lane < 48) ? s1 : s2;
    f32x4 v = *reinterpret_cast<const f32x4*>(b + col);   // aligned
    store4_u(o + col, v);
  }
  // k=1: cols 259+4*lane in [259,515): t2 (lane<48), t3 (else)
  {
    int col = 259 + 4 * lane;
    const float* b = (lane < 48) ? s2 : s3;
    f32x4 v = *reinterpret_cast<const f32x4*>(b + col);   // aligned
    store4_u(o + col, v);
  }
  // k=2: cols 515+4*lane in [515,771): all t3
  {
    int col = 515 + 4 * lane;
    f32x4 v = *reinterpret_cast<const f32x4*>(s3 + col);  // aligned
    store4_u(o + col, v);
  }
  // k=3: cols 771+4*lane in [771,963) for lane<48: all t3
  if (lane < 48) {
    int col = 771 + 4 * lane;
    f32x4 v = *reinterpret_cast<const f32x4*>(s3 + col);  // aligned
    store4_u(o + col, v);
  }
}

// ---------- fallback paths (small workspace) ----------
__device__ __forceinline__ void proj_hw(const float* __restrict__ verts, int n,
                                        float& h, float& w) {
  float v0 = verts[3 * n + 0];
  float v1 = verts[3 * n + 1];
  float v2 = verts[3 * n + 2];
  h = __fadd_rn(__fmul_rn(248.0f, __fdiv_rn(v1, v2)), 111.5f);
  w = __fadd_rn(__fmul_rn(248.0f, __fdiv_rn(v0, -v2)), 111.5f);
  h = fminf(fmaxf(h, 0.0f), 223.0f);
  w = fminf(fmaxf(w, 0.0f), 223.0f);
}

template <int MODE>
__device__ __forceinline__ int get_off(const int* __restrict__ params,
                                       const float* __restrict__ verts,
                                       int n, int k, float scale, int S) {
  if (MODE < 2) return params[4 * n + k];
  float h, w;
  proj_hw(verts, n, h, w);
  return level_off(h, w, scale, S);
}

__global__ __launch_bounds__(256) void prep_params_k(const float* __restrict__ verts,
                                                     int* __restrict__ params) {
  int n = blockIdx.x * 256 + threadIdx.x;
  if (n >= NV) return;
  float h, w;
  proj_hw(verts, n, h, w);
  params[4 * n + 0] = level_off(h, w, 0.25f,    56);
  params[4 * n + 1] = level_off(h, w, 0.125f,   28);
  params[4 * n + 2] = level_off(h, w, 0.0625f,  14);
  params[4 * n + 3] = level_off(h, w, 0.03125f, 7);
}

static constexpr int B_VERTS = 3 * NV;            // 150,000
static constexpr int B_F0    = B_VERTS + 64 * NV; // 3,350,000
static constexpr int B_F1    = B_F0 + 128 * NV;   // 9,750,000
static constexpr int B_F2    = B_F1 + 256 * NV;   // 22,550,000

template <int MODE>
__global__ __launch_bounds__(256) void gp_main_k(
    const float* __restrict__ verts,
    const float* __restrict__ f0, const float* __restrict__ f1,
    const float* __restrict__ f2, const float* __restrict__ f3,
    const int* __restrict__ params, float* __restrict__ out) {
  int j = blockIdx.x * 256 + threadIdx.x;
  if (j >= TOTAL) return;

  if (j < B_VERTS) {
    int n = j / 3;
    int col = j - 3 * n;
    out[n * 963 + col] = verts[j];
    return;
  }

  int n, outcol;
  float val = 0.0f;
  if (j < B_F0) {
    int t = j - B_VERTS; n = t >> 6; int c = t & 63;
    int off = get_off<MODE>(params, verts, n, 0, 0.25f, 56);
    if (off >= 0) val = f0[c * 3136 + off];
    outcol = 3 + c;
  } else if (j < B_F1) {
    int t = j - B_F0; n = t >> 7; int c = t & 127;
    int off = get_off<MODE>(params, verts, n, 1, 0.125f, 28);
    if (off >= 0) val = f1[c * 784 + off];
    outcol = 67 + c;
  } else if (j < B_F2) {
    int t = j - B_F1; n = t >> 8; int c = t & 255;
    int off = get_off<MODE>(params, verts, n, 2, 0.0625f, 14);
    if (off >= 0) val = f2[c * 196 + off];
    outcol = 195 + c;
  } else {
    int t = j - B_F2; n = t >> 9; int c = t & 511;
    int off = get_off<MODE>(params, verts, n, 3, 0.03125f, 7);
    if (off >= 0) val = f3[c * 49 + off];
    outcol = 451 + c;
  }
  out[n * 963 + outcol] = val;
}

extern "C" void kernel_launch(void* const* d_in, const int* in_sizes, int n_in,
                              void* d_out, int out_size, void* d_ws, size_t ws_size,
                              hipStream_t stream) {
  const float* f0    = (const float*)d_in[0];
  const float* f1    = (const float*)d_in[1];
  const float* f2    = (const float*)d_in[2];
  const float* f3    = (const float*)d_in[3];
  const float* verts = (const float*)d_in[4];
  float* out = (float*)d_out;

  const size_t PARAM_BYTES = (size_t)NV * 4 * sizeof(int);        // 800,000
  const size_t FAST_BYTES  = (size_t)(TSUM + ZN) * sizeof(float); // 1,507,344

  if (ws_size >= FAST_BYTES) {
    float* t0 = (float*)d_ws;
    float* t1 = t0 + T0;
    float* t2 = t1 + T1;
    float* t3 = t2 + T2;
    float* zeros = t3 + T3;
    transpose_k<<<(TSUM + ZN + 255) / 256, 256, 0, stream>>>(f0, f1, f2, f3,
                                                             t0, t1, t2, t3, zeros);
    const int rowBlocks = (NV * 64 + 255) / 256;  // 12,500 (one wave per vertex)
    gp_row_k<<<rowBlocks, 256, 0, stream>>>(verts, t0, t1, t2, t3, zeros, out);
  } else if (ws_size >= PARAM_BYTES) {
    int* params = (int*)d_ws;
    prep_params_k<<<(NV + 255) / 256, 256, 0, stream>>>(verts, params);
    gp_main_k<1><<<(TOTAL + 255) / 256, 256, 0, stream>>>(verts, f0, f1, f2, f3, params, out);
  } else {
    gp_main_k<2><<<(TOTAL + 255) / 256, 256, 0, stream>>>(verts, f0, f1, f2, f3, nullptr, out);
  }
}